// Round 8
// baseline (120.457 us; speedup 1.0000x reference)
//
#include <hip/hip_runtime.h>
#include <hip/hip_bf16.h>

// WaveletLinear: y[b,o] = sum_i w[o,i] * (1 - s^2) * exp(-0.5 s^2),
//   s = (x[b,i] - t[o,i]) / (A_MIN + softplus(sr[o,i]) + EPS)
// u = K*s^2 (K = 0.5*log2 e); e = exp2(-u); y = sum w * [e * (1 - u/K)].
//
// R8: R7's grid/structure (2048 blocks x 4 waves, lane=o, b-tile 4, proven
// 7 MB FETCH / no spill) + packed-f16 inner math. R7 busy model was exact:
// 88 cyc/step = 40 pk_f32 (HALF-rate: no gain) + 32 exp + 16 other.
// v_pk_fma_f16 is FULL-rate (2 ops / 2 cyc) and v_fma_mix_f32 accumulates
// f16 inputs into f32 accs at full rate -> step drops to ~64 cyc.
// Params precomputed as f16x4 {nti, inv_s, w, 0} (8 B -> dwordx2 loads);
// x staged into LDS as f16 (uniform ds_read_b64). Accumulation stays f32.

#define WL_A_MIN 0.001f
#define WL_EPS   1e-8f

constexpr int WL_B = 512;
constexpr int WL_O = 1024;
constexpr int WL_I = 512;

#define WL_SQK  0.84932180553704583800f   // sqrt(0.5*log2 e)
#define WL_IK   1.38629436111989061883f   // 1/K = 2 ln 2
#define WL_L2E  1.44269504088896340736f
#define WL_LN2  0.69314718055994530942f

typedef _Float16 h2 __attribute__((ext_vector_type(2)));
typedef _Float16 h4 __attribute__((ext_vector_type(4)));

__device__ __forceinline__ float fast_exp2(float a) {
#if __has_builtin(__builtin_amdgcn_exp2f)
    return __builtin_amdgcn_exp2f(a);
#else
    return exp2f(a);
#endif
}
__device__ __forceinline__ float fast_log2(float a) {
#if __has_builtin(__builtin_amdgcn_logf)
    return __builtin_amdgcn_logf(a);
#else
    return __log2f(a);
#endif
}
__device__ __forceinline__ float fast_rcp(float a) {
#if __has_builtin(__builtin_amdgcn_rcpf)
    return __builtin_amdgcn_rcpf(a);
#else
    return 1.0f / a;
#endif
}

// Param precompute (f32 math, f16 store): pT[i*1024 + o] = {nti, inv_s, w, 0}.
__global__ __launch_bounds__(256) void wl_prep(
    const float* __restrict__ translation,
    const float* __restrict__ scale_raw,
    const float* __restrict__ weights,
    h4* __restrict__ pT)
{
    const int lane   = threadIdx.x & 63;
    const int ic     = threadIdx.x >> 6;               // 0..3
    const int o      = blockIdx.x * 64 + lane;
    const int i_base = blockIdx.y * 64 + ic * 16;

    #pragma unroll 4
    for (int k = 0; k < 16; ++k) {
        int i  = i_base + k;
        int gi = o * WL_I + i;
        float t  = translation[gi];
        float sr = scale_raw[gi];
        float w  = weights[gi];
        float ex    = fast_exp2(sr * WL_L2E);          // softplus via hw exp2/log2
        float sp    = fast_log2(1.0f + ex) * WL_LN2;
        float inv   = fast_rcp(WL_A_MIN + sp + WL_EPS);
        float inv_s = inv * WL_SQK;
        h4 pv;
        pv.x = (_Float16)(-t * inv_s);
        pv.y = (_Float16)inv_s;
        pv.z = (_Float16)w;
        pv.w = (_Float16)0.0f;
        pT[(size_t)i * WL_O + o] = pv;
    }
}

// Reduction scratch: region per wave (3 dump regions), value k (0..3),
// addr = r*272 + k*68 + lane -> bank (4k+lane)%32: 2-way max = free.
constexpr int R_KS  = 68;
constexpr int R_REG = 4 * R_KS;                        // 272

__global__ __launch_bounds__(256, 6) void wl_main(
    const float* __restrict__ x,
    const h4* __restrict__ pT,
    float* __restrict__ out)
{
    __shared__ float smem[1280];   // 5 KB: [0,1024) = xT f16 (512 i x 4 b);
                                   // reduction reuses [0,816) after barrier.

    const int tid  = threadIdx.x;
    const int lane = tid & 63;
    const int wid  = tid >> 6;             // 0..3 = i-quarter
    const int o    = blockIdx.x * 64 + lane;
    const int b0   = blockIdx.y * 4;

    // ---- stage xT[i] = {x[b0..b0+3][i]} as f16x4; coalesced row loads ----
    #pragma unroll
    for (int c = 0; c < 2; ++c) {
        int i = c * 256 + tid;
        float a0 = x[(size_t)(b0 + 0) * WL_I + i];
        float a1 = x[(size_t)(b0 + 1) * WL_I + i];
        float a2 = x[(size_t)(b0 + 2) * WL_I + i];
        float a3 = x[(size_t)(b0 + 3) * WL_I + i];
        h4 v = {(_Float16)a0, (_Float16)a1, (_Float16)a2, (_Float16)a3};
        *reinterpret_cast<h4*>(&smem[i * 2]) = v;      // 8 B @ offset i*8
    }
    __syncthreads();

    const h4* pp = pT + o;
    const h2* xt = reinterpret_cast<const h2*>(smem);

    float a0 = 0.f, a1 = 0.f, a2 = 0.f, a3 = 0.f;
    const h2 one2 = {(_Float16)1.0f, (_Float16)1.0f};
    const h2 nIK2 = {(_Float16)(-WL_IK), (_Float16)(-WL_IK)};

    const int iBeg = wid * 128;
    #pragma unroll 8
    for (int ii = 0; ii < 128; ++ii) {
        const int i = iBeg + ii;
        h4 p  = pp[(size_t)i * WL_O];                  // 512B/wave dwordx2
        h2 xA = xt[i * 2];                             // uniform ds_read_b64
        h2 xB = xt[i * 2 + 1];

        h2 nti2 = {p.x, p.x};                          // op_sel broadcast
        h2 inv2 = {p.y, p.y};

        h2 sA = __builtin_elementwise_fma(xA, inv2, nti2);   // v_pk_fma_f16
        h2 sB = __builtin_elementwise_fma(xB, inv2, nti2);
        h2 uA = sA * sA;                                     // v_pk_mul_f16
        h2 uB = sB * sB;
        h2 eA = __builtin_elementwise_exp2(-uA);             // 2x v_exp_f16
        h2 eB = __builtin_elementwise_exp2(-uB);
        h2 tA = __builtin_elementwise_fma(uA, nIK2, one2);   // 1 - u/K
        h2 tB = __builtin_elementwise_fma(uB, nIK2, one2);
        h2 gA = eA * tA;
        h2 gB = eB * tB;

        // f32 accumulate via v_fma_mix_f32 (f16 srcs, f32 acc)
        a0 = fmaf((float)p.z, (float)gA.x, a0);
        a1 = fmaf((float)p.z, (float)gA.y, a1);
        a2 = fmaf((float)p.z, (float)gB.x, a2);
        a3 = fmaf((float)p.z, (float)gB.y, a3);
    }

    // ---- cross-wave reduction: waves 1..3 dump, wave 0 combines + stores ----
    __syncthreads();                                   // done reading xT
    if (wid != 0) {
        float* r = &smem[(wid - 1) * R_REG + lane];
        r[0 * R_KS] = a0; r[1 * R_KS] = a1;
        r[2 * R_KS] = a2; r[3 * R_KS] = a3;
    }
    __syncthreads();
    if (wid == 0) {
        #pragma unroll
        for (int q = 0; q < 3; ++q) {
            const float* r = &smem[q * R_REG + lane];
            a0 += r[0 * R_KS]; a1 += r[1 * R_KS];
            a2 += r[2 * R_KS]; a3 += r[3 * R_KS];
        }
        out[(size_t)(b0 + 0) * WL_O + o] = a0;
        out[(size_t)(b0 + 1) * WL_O + o] = a1;
        out[(size_t)(b0 + 2) * WL_O + o] = a2;
        out[(size_t)(b0 + 3) * WL_O + o] = a3;
    }
}

extern "C" void kernel_launch(void* const* d_in, const int* in_sizes, int n_in,
                              void* d_out, int out_size, void* d_ws, size_t ws_size,
                              hipStream_t stream) {
    const float* x           = (const float*)d_in[0];
    const float* translation = (const float*)d_in[1];
    const float* scale_raw   = (const float*)d_in[2];
    const float* weights     = (const float*)d_in[3];
    float*       out         = (float*)d_out;
    h4*          pT          = (h4*)d_ws;              // 4 MB

    wl_prep<<<dim3(WL_O / 64, WL_I / 64), dim3(256), 0, stream>>>(
        translation, scale_raw, weights, pT);

    // grid (o-slabs, b-tiles): bid%8 = gx%8 -> XCD k caches slabs {k, k+8}.
    wl_main<<<dim3(WL_O / 64, WL_B / 4), dim3(256), 0, stream>>>(x, pT, out);
}

// Round 10
// 119.718 us; speedup vs baseline: 1.0062x; 1.0062x over previous
//
#include <hip/hip_runtime.h>
#include <hip/hip_bf16.h>

// WaveletLinear: y[b,o] = sum_i w[o,i] * (1 - s^2) * exp(-0.5 s^2),
//   s = (x[b,i] - t[o,i]) / (A_MIN + softplus(sr[o,i]) + EPS)
// u = K*s^2 (K = 0.5*log2 e), e = exp2(-u), y = sum w * [e * (1 - u/K)].
//
// R10 = R9 with the assembler-rejected `v_exp_f16 ... op_sel` replaced by
// lshr+exp+v_pack_b32_f16 (R9's error showed plain `v_exp_f16_e64 d, -s`
// DOES assemble; op_sel on VOP1-promoted transcendentals does not).
// Step: 2 pk_fma(s) + 2 pk_mul(u) + 2 lshr + 4 v_exp_f16(-u) + 2 pack +
// 2 pk_fma(t=1-u/K) + 2 pk_mul(g=e*t) + 4 v_fma_mix_f32 (f16->f32 acc)
// ~= 70 cyc vs R7's measured 88.

#define WL_A_MIN 0.001f
#define WL_EPS   1e-8f

constexpr int WL_B = 512;
constexpr int WL_O = 1024;
constexpr int WL_I = 512;

#define WL_SQK  0.84932180553704583800f   // sqrt(0.5*log2 e)
#define WL_IK   1.38629436111989061883f   // 1/K = 2 ln 2
#define WL_L2E  1.44269504088896340736f
#define WL_LN2  0.69314718055994530942f

typedef _Float16 h4 __attribute__((ext_vector_type(4)));
typedef unsigned int u32;

struct PU3 { u32 nti2, inv2, w2; };        // 12 B, each = f16 value duplicated

__device__ __forceinline__ float fast_exp2(float a) {
#if __has_builtin(__builtin_amdgcn_exp2f)
    return __builtin_amdgcn_exp2f(a);
#else
    return exp2f(a);
#endif
}
__device__ __forceinline__ float fast_log2(float a) {
#if __has_builtin(__builtin_amdgcn_logf)
    return __builtin_amdgcn_logf(a);
#else
    return __log2f(a);
#endif
}
__device__ __forceinline__ float fast_rcp(float a) {
#if __has_builtin(__builtin_amdgcn_rcpf)
    return __builtin_amdgcn_rcpf(a);
#else
    return 1.0f / a;
#endif
}
__device__ __forceinline__ u32 dup16(float v) {
    _Float16 h = (_Float16)v;
    unsigned short b = __builtin_bit_cast(unsigned short, h);
    return (u32)b * 0x10001u;
}

// Param precompute: pT[i*1024 + o] = {nti2, inv2, w2} (f16 duplicated pairs).
__global__ __launch_bounds__(256) void wl_prep(
    const float* __restrict__ translation,
    const float* __restrict__ scale_raw,
    const float* __restrict__ weights,
    PU3* __restrict__ pT)
{
    const int lane   = threadIdx.x & 63;
    const int ic     = threadIdx.x >> 6;               // 0..3
    const int o      = blockIdx.x * 64 + lane;
    const int i_base = blockIdx.y * 64 + ic * 16;

    #pragma unroll 4
    for (int k = 0; k < 16; ++k) {
        int i  = i_base + k;
        int gi = o * WL_I + i;
        float t  = translation[gi];
        float sr = scale_raw[gi];
        float w  = weights[gi];
        float ex    = fast_exp2(sr * WL_L2E);          // softplus via hw exp2/log2
        float sp    = fast_log2(1.0f + ex) * WL_LN2;
        float inv   = fast_rcp(WL_A_MIN + sp + WL_EPS);
        float inv_s = inv * WL_SQK;
        PU3 pv;
        pv.nti2 = dup16(-t * inv_s);
        pv.inv2 = dup16(inv_s);
        pv.w2   = dup16(w);
        pT[(size_t)i * WL_O + o] = pv;
    }
}

// Reduction scratch: 3 regions x 4 values, addr = r*272 + k*68 + lane
// -> bank (4k+lane)%32 = 2-way max (free).
constexpr int R_KS  = 68;
constexpr int R_REG = 4 * R_KS;                        // 272

__global__ __launch_bounds__(256, 6) void wl_main(
    const float* __restrict__ x,
    const PU3* __restrict__ pT,
    float* __restrict__ out)
{
    __shared__ u32 smem[1024];             // 4 KB: xT h2-pairs; reduction reuses

    const int tid  = threadIdx.x;
    const int lane = tid & 63;
    const int wid  = tid >> 6;             // 0..3 = i-quarter
    const int o    = blockIdx.x * 64 + lane;
    const int b0   = blockIdx.y * 4;

    // ---- stage xT[i] = 4 b as 2 h2 words; coalesced row loads ----
    #pragma unroll
    for (int c = 0; c < 2; ++c) {
        int i = c * 256 + tid;
        float a0 = x[(size_t)(b0 + 0) * WL_I + i];
        float a1 = x[(size_t)(b0 + 1) * WL_I + i];
        float a2 = x[(size_t)(b0 + 2) * WL_I + i];
        float a3 = x[(size_t)(b0 + 3) * WL_I + i];
        h4 v = {(_Float16)a0, (_Float16)a1, (_Float16)a2, (_Float16)a3};
        *reinterpret_cast<h4*>(&smem[i * 2]) = v;      // 8 B
    }
    __syncthreads();

    const PU3* pp = pT + o;

    float a0 = 0.f, a1 = 0.f, a2 = 0.f, a3 = 0.f;
    const u32 one2 = 0x3C003C00u;          // f16 {1,1}
    const u32 nIK2 = dup16(-WL_IK);        // f16 {-1/K, -1/K} (const-folded)

    const int iBeg = wid * 128;
    #pragma unroll 8
    for (int ii = 0; ii < 128; ++ii) {
        const int i = iBeg + ii;
        PU3 p = pp[(size_t)i * WL_O];                  // global dwordx3, 768B/wave
        uint2 xw = *reinterpret_cast<const uint2*>(&smem[i * 2]);  // uniform b64

        u32 sA, sB, uA, uB, hA, hB, elA, ehA, elB, ehB, eA, eB, tA, tB, gA, gB;
        asm("v_pk_fma_f16 %0, %1, %2, %3" : "=v"(sA) : "v"(xw.x), "v"(p.inv2), "v"(p.nti2));
        asm("v_pk_fma_f16 %0, %1, %2, %3" : "=v"(sB) : "v"(xw.y), "v"(p.inv2), "v"(p.nti2));
        asm("v_pk_mul_f16 %0, %1, %1" : "=v"(uA) : "v"(sA));
        asm("v_pk_mul_f16 %0, %1, %1" : "=v"(uB) : "v"(sB));
        // e = exp2(-u): lo half direct; hi half via lshr; recombine with pack.
        asm("v_lshrrev_b32 %0, 16, %1" : "=v"(hA) : "v"(uA));
        asm("v_lshrrev_b32 %0, 16, %1" : "=v"(hB) : "v"(uB));
        asm("v_exp_f16_e64 %0, -%1" : "=v"(elA) : "v"(uA));
        asm("v_exp_f16_e64 %0, -%1" : "=v"(ehA) : "v"(hA));
        asm("v_exp_f16_e64 %0, -%1" : "=v"(elB) : "v"(uB));
        asm("v_exp_f16_e64 %0, -%1" : "=v"(ehB) : "v"(hB));
        asm("v_pack_b32_f16 %0, %1, %2" : "=v"(eA) : "v"(elA), "v"(ehA));
        asm("v_pack_b32_f16 %0, %1, %2" : "=v"(eB) : "v"(elB), "v"(ehB));
        // t = 1 - u/K ; g = e * t
        asm("v_pk_fma_f16 %0, %1, %2, %3" : "=v"(tA) : "v"(uA), "v"(nIK2), "v"(one2));
        asm("v_pk_fma_f16 %0, %1, %2, %3" : "=v"(tB) : "v"(uB), "v"(nIK2), "v"(one2));
        asm("v_pk_mul_f16 %0, %1, %2" : "=v"(gA) : "v"(eA), "v"(tA));
        asm("v_pk_mul_f16 %0, %1, %2" : "=v"(gB) : "v"(eB), "v"(tB));
        // f32 accumulate: acc += w * g   (f16 srcs via op_sel, f32 acc)
        asm("v_fma_mix_f32 %0, %1, %2, %0 op_sel:[0,0,0] op_sel_hi:[1,1,0]"
            : "+v"(a0) : "v"(p.w2), "v"(gA));
        asm("v_fma_mix_f32 %0, %1, %2, %0 op_sel:[1,1,0] op_sel_hi:[1,1,0]"
            : "+v"(a1) : "v"(p.w2), "v"(gA));
        asm("v_fma_mix_f32 %0, %1, %2, %0 op_sel:[0,0,0] op_sel_hi:[1,1,0]"
            : "+v"(a2) : "v"(p.w2), "v"(gB));
        asm("v_fma_mix_f32 %0, %1, %2, %0 op_sel:[1,1,0] op_sel_hi:[1,1,0]"
            : "+v"(a3) : "v"(p.w2), "v"(gB));
    }

    // ---- cross-wave reduction: waves 1..3 dump, wave 0 combines + stores ----
    __syncthreads();                                   // done reading xT
    float* smf = reinterpret_cast<float*>(smem);
    if (wid != 0) {
        float* r = &smf[(wid - 1) * R_REG + lane];
        r[0 * R_KS] = a0; r[1 * R_KS] = a1;
        r[2 * R_KS] = a2; r[3 * R_KS] = a3;
    }
    __syncthreads();
    if (wid == 0) {
        #pragma unroll
        for (int q = 0; q < 3; ++q) {
            const float* r = &smf[q * R_REG + lane];
            a0 += r[0 * R_KS]; a1 += r[1 * R_KS];
            a2 += r[2 * R_KS]; a3 += r[3 * R_KS];
        }
        out[(size_t)(b0 + 0) * WL_O + o] = a0;
        out[(size_t)(b0 + 1) * WL_O + o] = a1;
        out[(size_t)(b0 + 2) * WL_O + o] = a2;
        out[(size_t)(b0 + 3) * WL_O + o] = a3;
    }
}

extern "C" void kernel_launch(void* const* d_in, const int* in_sizes, int n_in,
                              void* d_out, int out_size, void* d_ws, size_t ws_size,
                              hipStream_t stream) {
    const float* x           = (const float*)d_in[0];
    const float* translation = (const float*)d_in[1];
    const float* scale_raw   = (const float*)d_in[2];
    const float* weights     = (const float*)d_in[3];
    float*       out         = (float*)d_out;
    PU3*         pT          = (PU3*)d_ws;             // 6.3 MB

    wl_prep<<<dim3(WL_O / 64, WL_I / 64), dim3(256), 0, stream>>>(
        translation, scale_raw, weights, pT);

    // grid (o-slabs, b-tiles): bid%8 = gx%8 -> XCD k caches slabs {k, k+8}.
    wl_main<<<dim3(WL_O / 64, WL_B / 4), dim3(256), 0, stream>>>(x, pT, out);
}